// Round 1
// baseline (474.640 us; speedup 1.0000x reference)
//
#include <hip/hip_runtime.h>
#include <hip/hip_bf16.h>

#define N4 12000
#define N8 6000
#define NTOT 18000

// ---------- dtype-polymorphic loads (BF16 = harness converted fp32->bf16) ----------
template<bool BF16>
__device__ __forceinline__ float loadf(const void* p, long i) {
    if constexpr (BF16) {
        unsigned short v = ((const unsigned short*)p)[i];
        return __uint_as_float(((unsigned int)v) << 16);
    } else {
        return ((const float*)p)[i];
    }
}

template<bool BF16>
__device__ __forceinline__ void loadpair(const void* p, long pairIdx, float& a, float& b) {
    if constexpr (BF16) {
        unsigned int u = ((const unsigned int*)p)[pairIdx];
        a = __uint_as_float(u << 16);
        b = __uint_as_float(u & 0xffff0000u);
    } else {
        float2 v = ((const float2*)p)[pairIdx];
        a = v.x; b = v.y;
    }
}

template<bool BF16>
__device__ __forceinline__ void load8(const void* p, long elemIdx, float* out) {
    if constexpr (BF16) {
        uint4 u = *(const uint4*)(((const unsigned short*)p) + elemIdx);  // 8 bf16 = 16B
        out[0] = __uint_as_float(u.x << 16); out[1] = __uint_as_float(u.x & 0xffff0000u);
        out[2] = __uint_as_float(u.y << 16); out[3] = __uint_as_float(u.y & 0xffff0000u);
        out[4] = __uint_as_float(u.z << 16); out[5] = __uint_as_float(u.z & 0xffff0000u);
        out[6] = __uint_as_float(u.w << 16); out[7] = __uint_as_float(u.w & 0xffff0000u);
    } else {
        const float4* f = (const float4*)(((const float*)p) + elemIdx);
        float4 a = f[0], b = f[1];
        out[0] = a.x; out[1] = a.y; out[2] = a.z; out[3] = a.w;
        out[4] = b.x; out[5] = b.y; out[6] = b.z; out[7] = b.w;
    }
}

// ---------- dtype detection: fp32 data read as bf16 at even positions is wild ----------
__global__ void k_detect(const void* W, int* flag, float* acc) {
    if (threadIdx.x == 0 && blockIdx.x == 0) {
        const unsigned short* u = (const unsigned short*)W;
        int bf = 1;
        for (int i = 0; i < 256; i++) {
            float f = __uint_as_float(((unsigned int)u[i]) << 16);
            if (!(fabsf(f) < 1.0f)) bf = 0;  // W ~ N(0, 0.02^2): |W| << 1 if truly bf16
        }
        *flag = bf;
        *acc = 0.0f;
    }
}

// ---------- per-row body: one wave handles one group row ----------
template<bool BF16>
__device__ __forceinline__ void row_body(
    int row, int lane, float* nrow,
    const void* n, const void* e, const void* W, const void* bptr,
    const int* hn4, const int* he4, const int* hn8, const int* he8,
    float* acc)
{
    int k, node;
    const int* ebase;
    if (row < N4) { k = 4; node = hn4[row]; ebase = he4 + (long)row * 64; }
    else { int r = row - N4; k = 8; node = hn8[r]; ebase = he8 + (long)r * 128; }

    const float bval = loadf<BF16>(bptr, 0);

    // stage n_row into this wave's private LDS slice (broadcast source)
    long nb = (long)node * 128;
    nrow[lane]      = loadf<BF16>(n, nb + lane);
    nrow[lane + 64] = loadf<BF16>(n, nb + 64 + lane);

    // matvec t = n_row @ W ; lane owns outputs o = 2*lane, 2*lane+1
    float t0 = 0.0f, t1 = 0.0f;
#pragma unroll 8
    for (int c = 0; c < 128; c++) {
        float nc = nrow[c];                        // LDS broadcast (free)
        float w0, w1;
        loadpair<BF16>(W, (long)c * 64 + lane, w0, w1);  // coalesced, L1-resident
        t0 = fmaf(nc, w0, t0);
        t1 = fmaf(nc, w1, t1);
    }

    // round-trip t through LDS so each lane gets its contiguous 8-wide slice
    nrow[2 * lane]     = t0;
    nrow[2 * lane + 1] = t1;

    const int sub = lane & 15;   // position within the 16-lane dot group
    const int grp = lane >> 4;   // which of 4 dots per chunk

    float tf[8];
    {
        const float4* p4 = (const float4*)nrow;
        float4 a = p4[sub * 2], b = p4[sub * 2 + 1];
        tf[0] = a.x; tf[1] = a.y; tf[2] = a.z; tf[3] = a.w;
        tf[4] = b.x; tf[5] = b.y; tf[6] = b.z; tf[7] = b.w;
    }

    float sacc[8];
#pragma unroll
    for (int j = 0; j < 8; j++) sacc[j] = 0.0f;

    // chunks of 4 dot-products; chunk ch covers j = ch>>2, d = 4*(ch&3)+grp
    const int nch = k * 4;
    for (int ch = 0; ch < nch; ch++) {
        int flat = ch * 4 + grp;         // = j*16 + d, row-major [k,D]
        int eidx = ebase[flat];
        float ev[8];
        load8<BF16>(e, (long)eidx * 128 + sub * 8, ev);  // 16B coalesced within group
        float dot = tf[0] * ev[0];
#pragma unroll
        for (int q = 1; q < 8; q++) dot = fmaf(tf[q], ev[q], dot);
        dot += __shfl_xor(dot, 1);
        dot += __shfl_xor(dot, 2);
        dot += __shfl_xor(dot, 4);
        dot += __shfl_xor(dot, 8);       // full dot in all 16 lanes of the group
        float logit = dot + bval;
        float sig = 1.0f / (1.0f + __expf(-logit));
        float ex = __expf(sig * 2.0f);   // exp(sigmoid/TAU), TAU=0.5
        if (sub == 0) sacc[ch >> 2] += ex;
    }

    // reduce each s[j] across the wave (partials live at lanes 0,16,32,48)
    float s_all[8];
#pragma unroll
    for (int j = 0; j < 8; j++) {
        float v = (j < k) ? sacc[j] : 0.0f;
        v += __shfl_xor(v, 16);
        v += __shfl_xor(v, 32);
        s_all[j] = v;                    // correct total at lane 0
    }

    if (lane == 0) {
        float suffix = s_all[k - 1];
        float lsum = 0.0f;
        for (int j = k - 2; j >= 0; j--) {
            suffix += s_all[j];
            float ratio = s_all[j] / suffix;
            ratio = fminf(ratio, 10.0f); // BETA
            lsum += -__logf(ratio);
        }
        atomicAdd(acc, lsum / (float)(k - 1));
    }
}

__global__ __launch_bounds__(256) void k_rows(
    const void* n, const void* e, const void* W, const void* bptr,
    const int* hn4, const int* he4, const int* hn8, const int* he8,
    const int* flag, float* acc)
{
    __shared__ __align__(16) float nlds[4 * 128];
    const int lane = threadIdx.x & 63;
    const int wave = threadIdx.x >> 6;
    const int row = blockIdx.x * 4 + wave;
    float* nrow = nlds + wave * 128;
    const bool bf = (*flag != 0);  // runtime-uniform across the whole grid
    if (bf) row_body<true >(row, lane, nrow, n, e, W, bptr, hn4, he4, hn8, he8, acc);
    else    row_body<false>(row, lane, nrow, n, e, W, bptr, hn4, he4, hn8, he8, acc);
}

__global__ void k_final(const float* acc, const int* flag, void* out) {
    if (threadIdx.x == 0 && blockIdx.x == 0) {
        float m = *acc / (float)NTOT;
        if (*flag) ((__hip_bfloat16*)out)[0] = __float2bfloat16(m);
        else       ((float*)out)[0] = m;
    }
}

extern "C" void kernel_launch(void* const* d_in, const int* in_sizes, int n_in,
                              void* d_out, int out_size, void* d_ws, size_t ws_size,
                              hipStream_t stream) {
    const void* n    = d_in[0];
    const void* e    = d_in[1];
    const void* W    = d_in[2];
    const void* bptr = d_in[3];
    const int* hn4 = (const int*)d_in[4];
    const int* he4 = (const int*)d_in[5];
    const int* hn8 = (const int*)d_in[6];
    const int* he8 = (const int*)d_in[7];

    float* acc = (float*)d_ws;
    int* flag  = ((int*)d_ws) + 1;

    k_detect<<<1, 64, 0, stream>>>(W, flag, acc);
    k_rows<<<NTOT / 4, 256, 0, stream>>>(n, e, W, bptr, hn4, he4, hn8, he8, flag, acc);
    k_final<<<1, 64, 0, stream>>>(acc, flag, d_out);
}

// Round 2
// 445.116 us; speedup vs baseline: 1.0663x; 1.0663x over previous
//
#include <hip/hip_runtime.h>
#include <hip/hip_bf16.h>

#define N4 12000
#define N8 6000
#define NTOT 18000

// ---------- dtype-polymorphic loads (BF16 = harness converted fp32->bf16) ----------
template<bool BF16>
__device__ __forceinline__ float loadf(const void* p, long i) {
    if constexpr (BF16) {
        unsigned short v = ((const unsigned short*)p)[i];
        return __uint_as_float(((unsigned int)v) << 16);
    } else {
        return ((const float*)p)[i];
    }
}

template<bool BF16>
__device__ __forceinline__ void loadpair(const void* p, long pairIdx, float& a, float& b) {
    if constexpr (BF16) {
        unsigned int u = ((const unsigned int*)p)[pairIdx];
        a = __uint_as_float(u << 16);
        b = __uint_as_float(u & 0xffff0000u);
    } else {
        float2 v = ((const float2*)p)[pairIdx];
        a = v.x; b = v.y;
    }
}

// raw (unconverted) gathered e-row fragment: 8 elements per lane
template<bool BF16> struct RawRow;
template<> struct RawRow<true> {
    uint4 v;
    __device__ __forceinline__ void ld(const void* e, int eidx, int sub) {
        v = *(const uint4*)(((const unsigned short*)e) + (long)eidx * 128 + sub * 8);
    }
    __device__ __forceinline__ void unpack(float* o) const {
        o[0] = __uint_as_float(v.x << 16); o[1] = __uint_as_float(v.x & 0xffff0000u);
        o[2] = __uint_as_float(v.y << 16); o[3] = __uint_as_float(v.y & 0xffff0000u);
        o[4] = __uint_as_float(v.z << 16); o[5] = __uint_as_float(v.z & 0xffff0000u);
        o[6] = __uint_as_float(v.w << 16); o[7] = __uint_as_float(v.w & 0xffff0000u);
    }
};
template<> struct RawRow<false> {
    float4 a, b;
    __device__ __forceinline__ void ld(const void* e, int eidx, int sub) {
        const float4* p = (const float4*)(((const float*)e) + (long)eidx * 128 + sub * 8);
        a = p[0]; b = p[1];
    }
    __device__ __forceinline__ void unpack(float* o) const {
        o[0] = a.x; o[1] = a.y; o[2] = a.z; o[3] = a.w;
        o[4] = b.x; o[5] = b.y; o[6] = b.z; o[7] = b.w;
    }
};

// ---------- dtype detection (parallel): fp32 read as bf16 at odd halves is wild ----------
__global__ void k_detect(const void* W, int* flag, float* acc) {
    const int lane = threadIdx.x;
    const unsigned short* u = (const unsigned short*)W;
    bool wild = false;
    for (int i = lane; i < 256; i += 64) {
        float f = __uint_as_float(((unsigned int)u[i]) << 16);
        if (!(fabsf(f) < 1.0f)) wild = true;   // W ~ N(0, 0.02^2): |W| << 1 if truly bf16
    }
    unsigned long long m = __ballot(wild);
    if (lane == 0) { *flag = (m == 0ull) ? 1 : 0; *acc = 0.0f; }
}

// ---------- per-row body: one wave per group row, K compile-time ----------
template<bool BF16, int K>
__device__ __forceinline__ void row_body(
    int lane, float* nrow, int node, const int* ebase,
    const void* n, const void* e, const void* W, const void* bptr,
    float* acc)
{
    const float bval = loadf<BF16>(bptr, 0);

    // stage n_row into this wave's private LDS slice (broadcast source)
    long nb = (long)node * 128;
    nrow[lane]      = loadf<BF16>(n, nb + lane);
    nrow[lane + 64] = loadf<BF16>(n, nb + 64 + lane);

    // matvec t = n_row @ W ; lane owns outputs o = 2*lane, 2*lane+1
    float t0 = 0.0f, t1 = 0.0f;
#pragma unroll 8
    for (int c = 0; c < 128; c++) {
        float nc = nrow[c];                              // LDS broadcast
        float w0, w1;
        loadpair<BF16>(W, (long)c * 64 + lane, w0, w1);  // coalesced, L1-resident
        t0 = fmaf(nc, w0, t0);
        t1 = fmaf(nc, w1, t1);
    }

    // round-trip t through LDS so each lane gets its contiguous 8-wide slice
    nrow[2 * lane]     = t0;
    nrow[2 * lane + 1] = t1;

    const int sub = lane & 15;   // element-slice owner within 16-lane dot group
    const int grp = lane >> 4;   // which quarter of the flat [K*16] chunk range

    float tf[8];
    {
        const float4* p4 = (const float4*)nrow;
        float4 a = p4[sub * 2], b = p4[sub * 2 + 1];
        tf[0] = a.x; tf[1] = a.y; tf[2] = a.z; tf[3] = a.w;
        tf[4] = b.x; tf[5] = b.y; tf[6] = b.z; tf[7] = b.w;
    }

    // group grp owns flat chunk indices [grp*NCH, (grp+1)*NCH) of the [K,16] grid
    constexpr int NCH = K * 4;          // chunks per group
    constexpr int NS  = K / 4;          // distinct j values per group
    constexpr int PF  = 8;              // prefetch depth (outstanding gathers/lane)

    // vectorized index load: lane's indices are contiguous under this mapping
    int idx[NCH];
    {
        const int4* ip = (const int4*)(ebase + grp * NCH);
#pragma unroll
        for (int t = 0; t < NCH / 4; t++) {
            int4 q = ip[t];
            idx[4 * t + 0] = q.x; idx[4 * t + 1] = q.y;
            idx[4 * t + 2] = q.z; idx[4 * t + 3] = q.w;
        }
    }

    RawRow<BF16> buf[PF];
#pragma unroll
    for (int i = 0; i < PF; i++) buf[i].ld(e, idx[i], sub);

    float sacc[NS];
#pragma unroll
    for (int i = 0; i < NS; i++) sacc[i] = 0.0f;

#pragma unroll
    for (int ch = 0; ch < NCH; ch++) {
        float ev[8];
        buf[ch % PF].unpack(ev);
        if (ch + PF < NCH) buf[ch % PF].ld(e, idx[ch + PF], sub);

        float dot = tf[0] * ev[0];
#pragma unroll
        for (int q = 1; q < 8; q++) dot = fmaf(tf[q], ev[q], dot);
        dot += __shfl_xor(dot, 1);
        dot += __shfl_xor(dot, 2);
        dot += __shfl_xor(dot, 4);
        dot += __shfl_xor(dot, 8);       // full dot replicated in all 16 group lanes

        float logit = dot + bval;
        float sig = 1.0f / (1.0f + __expf(-logit));
        float ex = __expf(sig * 2.0f);   // exp(sigmoid/TAU), TAU=0.5
        sacc[ch >> 4] += ex;             // identical across group lanes; j = grp*NS + (ch>>4)
    }

    // collect s[j]: owned by group j/NS (any of its lanes), slot j%NS
    float s_all[K];
#pragma unroll
    for (int j = 0; j < K; j++)
        s_all[j] = __shfl(sacc[j % NS], (j / NS) * 16);

    if (lane == 0) {
        float suffix = s_all[K - 1];
        float lsum = 0.0f;
#pragma unroll
        for (int j = K - 2; j >= 0; j--) {
            suffix += s_all[j];
            float ratio = fminf(s_all[j] / suffix, 10.0f);  // BETA
            lsum += -__logf(ratio);
        }
        atomicAdd(acc, lsum / (float)(K - 1));
    }
}

__global__ __launch_bounds__(256) void k_rows(
    const void* n, const void* e, const void* W, const void* bptr,
    const int* hn4, const int* he4, const int* hn8, const int* he8,
    const int* flag, float* acc)
{
    __shared__ __align__(16) float nlds[4 * 128];
    const int lane = threadIdx.x & 63;
    const int wave = threadIdx.x >> 6;
    const int row = blockIdx.x * 4 + wave;
    float* nrow = nlds + wave * 128;
    const bool bf = (*flag != 0);  // runtime-uniform across the whole grid

    if (row < N4) {
        int node = hn4[row];
        const int* ebase = he4 + (long)row * 64;
        if (bf) row_body<true,  4>(lane, nrow, node, ebase, n, e, W, bptr, acc);
        else    row_body<false, 4>(lane, nrow, node, ebase, n, e, W, bptr, acc);
    } else {
        int r = row - N4;
        int node = hn8[r];
        const int* ebase = he8 + (long)r * 128;
        if (bf) row_body<true,  8>(lane, nrow, node, ebase, n, e, W, bptr, acc);
        else    row_body<false, 8>(lane, nrow, node, ebase, n, e, W, bptr, acc);
    }
}

__global__ void k_final(const float* acc, const int* flag, void* out) {
    if (threadIdx.x == 0 && blockIdx.x == 0) {
        float m = *acc / (float)NTOT;
        if (*flag) ((__hip_bfloat16*)out)[0] = __float2bfloat16(m);
        else       ((float*)out)[0] = m;
    }
}

extern "C" void kernel_launch(void* const* d_in, const int* in_sizes, int n_in,
                              void* d_out, int out_size, void* d_ws, size_t ws_size,
                              hipStream_t stream) {
    const void* n    = d_in[0];
    const void* e    = d_in[1];
    const void* W    = d_in[2];
    const void* bptr = d_in[3];
    const int* hn4 = (const int*)d_in[4];
    const int* he4 = (const int*)d_in[5];
    const int* hn8 = (const int*)d_in[6];
    const int* he8 = (const int*)d_in[7];

    float* acc = (float*)d_ws;
    int* flag  = ((int*)d_ws) + 1;

    k_detect<<<1, 64, 0, stream>>>(W, flag, acc);
    k_rows<<<NTOT / 4, 256, 0, stream>>>(n, e, W, bptr, hn4, he4, hn8, he8, flag, acc);
    k_final<<<1, 64, 0, stream>>>(acc, flag, d_out);
}

// Round 3
// 333.052 us; speedup vs baseline: 1.4251x; 1.3365x over previous
//
#include <hip/hip_runtime.h>
#include <hip/hip_bf16.h>

#define N4 12000
#define N8 6000
#define NTOT 18000
#define NBLK (NTOT / 4)   // 4500 row-blocks, 4 waves each

// ---------- dtype-polymorphic loads (BF16 = harness converted fp32->bf16) ----------
template<bool BF16>
__device__ __forceinline__ float loadf(const void* p, long i) {
    if constexpr (BF16) {
        unsigned short v = ((const unsigned short*)p)[i];
        return __uint_as_float(((unsigned int)v) << 16);
    } else {
        return ((const float*)p)[i];
    }
}

template<bool BF16>
__device__ __forceinline__ void loadpair(const void* p, long pairIdx, float& a, float& b) {
    if constexpr (BF16) {
        unsigned int u = ((const unsigned int*)p)[pairIdx];
        a = __uint_as_float(u << 16);
        b = __uint_as_float(u & 0xffff0000u);
    } else {
        float2 v = ((const float2*)p)[pairIdx];
        a = v.x; b = v.y;
    }
}

// raw (unconverted) gathered e-row fragment: 8 elements per lane
template<bool BF16> struct RawRow;
template<> struct RawRow<true> {
    uint4 v;
    __device__ __forceinline__ void ld(const void* e, int eidx, int sub) {
        v = *(const uint4*)(((const unsigned short*)e) + (long)eidx * 128 + sub * 8);
    }
    __device__ __forceinline__ void unpack(float* o) const {
        o[0] = __uint_as_float(v.x << 16); o[1] = __uint_as_float(v.x & 0xffff0000u);
        o[2] = __uint_as_float(v.y << 16); o[3] = __uint_as_float(v.y & 0xffff0000u);
        o[4] = __uint_as_float(v.z << 16); o[5] = __uint_as_float(v.z & 0xffff0000u);
        o[6] = __uint_as_float(v.w << 16); o[7] = __uint_as_float(v.w & 0xffff0000u);
    }
};
template<> struct RawRow<false> {
    float4 a, b;
    __device__ __forceinline__ void ld(const void* e, int eidx, int sub) {
        const float4* p = (const float4*)(((const float*)e) + (long)eidx * 128 + sub * 8);
        a = p[0]; b = p[1];
    }
    __device__ __forceinline__ void unpack(float* o) const {
        o[0] = a.x; o[1] = a.y; o[2] = a.z; o[3] = a.w;
        o[4] = b.x; o[5] = b.y; o[6] = b.z; o[7] = b.w;
    }
};

// ---------- dtype detection (parallel): fp32 read as bf16 at odd halves is wild ----------
__global__ void k_detect(const void* W, int* flag) {
    const int lane = threadIdx.x;
    const unsigned short* u = (const unsigned short*)W;
    bool wild = false;
    for (int i = lane; i < 256; i += 64) {
        float f = __uint_as_float(((unsigned int)u[i]) << 16);
        if (!(fabsf(f) < 1.0f)) wild = true;   // W ~ N(0, 0.02^2): |W| << 1 if truly bf16
    }
    unsigned long long m = __ballot(wild);
    if (lane == 0) *flag = (m == 0ull) ? 1 : 0;
}

// ---------- per-row body: one wave per group row, K compile-time ----------
// Returns this row's loss (valid in lane 0 only).
template<bool BF16, int K>
__device__ __forceinline__ float row_body(
    int lane, float* nrow, int node, const int* ebase,
    const void* n, const void* e, const void* W, const void* bptr)
{
    const float bval = loadf<BF16>(bptr, 0);

    // stage n_row into this wave's private LDS slice (broadcast source)
    long nb = (long)node * 128;
    nrow[lane]      = loadf<BF16>(n, nb + lane);
    nrow[lane + 64] = loadf<BF16>(n, nb + 64 + lane);

    // matvec t = n_row @ W ; lane owns outputs o = 2*lane, 2*lane+1
    float t0 = 0.0f, t1 = 0.0f;
#pragma unroll 8
    for (int c = 0; c < 128; c++) {
        float nc = nrow[c];                              // LDS broadcast
        float w0, w1;
        loadpair<BF16>(W, (long)c * 64 + lane, w0, w1);  // coalesced, L1-resident
        t0 = fmaf(nc, w0, t0);
        t1 = fmaf(nc, w1, t1);
    }

    // round-trip t through LDS so each lane gets its contiguous 8-wide slice
    nrow[2 * lane]     = t0;
    nrow[2 * lane + 1] = t1;

    const int sub = lane & 15;   // element-slice owner within 16-lane dot group
    const int grp = lane >> 4;   // which quarter of the flat [K*16] chunk range

    float tf[8];
    {
        const float4* p4 = (const float4*)nrow;
        float4 a = p4[sub * 2], b = p4[sub * 2 + 1];
        tf[0] = a.x; tf[1] = a.y; tf[2] = a.z; tf[3] = a.w;
        tf[4] = b.x; tf[5] = b.y; tf[6] = b.z; tf[7] = b.w;
    }

    // group grp owns flat chunk indices [grp*NCH, (grp+1)*NCH) of the [K,16] grid
    constexpr int NCH = K * 4;          // chunks per group
    constexpr int NS  = K / 4;          // distinct j values per group
    constexpr int PF  = 8;              // prefetch depth (outstanding gathers/lane)

    int idx[NCH];
    {
        const int4* ip = (const int4*)(ebase + grp * NCH);
#pragma unroll
        for (int t = 0; t < NCH / 4; t++) {
            int4 q = ip[t];
            idx[4 * t + 0] = q.x; idx[4 * t + 1] = q.y;
            idx[4 * t + 2] = q.z; idx[4 * t + 3] = q.w;
        }
    }

    RawRow<BF16> buf[PF];
#pragma unroll
    for (int i = 0; i < PF; i++) buf[i].ld(e, idx[i], sub);

    float sacc[NS];
#pragma unroll
    for (int i = 0; i < NS; i++) sacc[i] = 0.0f;

#pragma unroll
    for (int ch = 0; ch < NCH; ch++) {
        float ev[8];
        buf[ch % PF].unpack(ev);
        if (ch + PF < NCH) buf[ch % PF].ld(e, idx[ch + PF], sub);

        float dot = tf[0] * ev[0];
#pragma unroll
        for (int q = 1; q < 8; q++) dot = fmaf(tf[q], ev[q], dot);
        dot += __shfl_xor(dot, 1);
        dot += __shfl_xor(dot, 2);
        dot += __shfl_xor(dot, 4);
        dot += __shfl_xor(dot, 8);       // full dot replicated in all 16 group lanes

        float logit = dot + bval;
        float sig = 1.0f / (1.0f + __expf(-logit));
        float ex = __expf(sig * 2.0f);   // exp(sigmoid/TAU), TAU=0.5
        sacc[ch >> 4] += ex;             // j = grp*NS + (ch>>4), same across group lanes
    }

    // collect s[j]: owned by group j/NS (any of its lanes), slot j%NS
    float s_all[K];
#pragma unroll
    for (int j = 0; j < K; j++)
        s_all[j] = __shfl(sacc[j % NS], (j / NS) * 16);

    float lsum = 0.0f;
    if (lane == 0) {
        float suffix = s_all[K - 1];
#pragma unroll
        for (int j = K - 2; j >= 0; j--) {
            suffix += s_all[j];
            float ratio = fminf(s_all[j] / suffix, 10.0f);  // BETA
            lsum += -__logf(ratio);
        }
        lsum /= (float)(K - 1);
    }
    return lsum;
}

__global__ __launch_bounds__(256) void k_rows(
    const void* n, const void* e, const void* W, const void* bptr,
    const int* hn4, const int* he4, const int* hn8, const int* he8,
    const int* flag, float* part)
{
    __shared__ __align__(16) float nlds[4 * 128];
    __shared__ float wsum[4];
    const int lane = threadIdx.x & 63;
    const int wave = threadIdx.x >> 6;
    const int row = blockIdx.x * 4 + wave;
    float* nrow = nlds + wave * 128;
    const bool bf = (*flag != 0);  // runtime-uniform across the whole grid

    float lsum;
    if (row < N4) {
        int node = hn4[row];
        const int* ebase = he4 + (long)row * 64;
        lsum = bf ? row_body<true, 4>(lane, nrow, node, ebase, n, e, W, bptr)
                  : row_body<false,4>(lane, nrow, node, ebase, n, e, W, bptr);
    } else {
        int r = row - N4;
        int node = hn8[r];
        const int* ebase = he8 + (long)r * 128;
        lsum = bf ? row_body<true, 8>(lane, nrow, node, ebase, n, e, W, bptr)
                  : row_body<false,8>(lane, nrow, node, ebase, n, e, W, bptr);
    }

    // one plain store per block — no global atomics (Guideline 12; same-address
    // atomicAdd from 18000 waves was the R1/R2 latency sink theory)
    if (lane == 0) wsum[wave] = lsum;
    __syncthreads();
    if (threadIdx.x == 0)
        part[blockIdx.x] = wsum[0] + wsum[1] + wsum[2] + wsum[3];
}

__global__ __launch_bounds__(256) void k_final(const float* part, const int* flag, void* out) {
    __shared__ float ws[4];
    const int tid = threadIdx.x;
    float v = 0.0f;
    for (int i = tid; i < NBLK; i += 256) v += part[i];
    v += __shfl_xor(v, 1);  v += __shfl_xor(v, 2);  v += __shfl_xor(v, 4);
    v += __shfl_xor(v, 8);  v += __shfl_xor(v, 16); v += __shfl_xor(v, 32);
    if ((tid & 63) == 0) ws[tid >> 6] = v;
    __syncthreads();
    if (tid == 0) {
        float m = (ws[0] + ws[1] + ws[2] + ws[3]) / (float)NTOT;
        if (*flag) ((__hip_bfloat16*)out)[0] = __float2bfloat16(m);
        else       ((float*)out)[0] = m;
    }
}

extern "C" void kernel_launch(void* const* d_in, const int* in_sizes, int n_in,
                              void* d_out, int out_size, void* d_ws, size_t ws_size,
                              hipStream_t stream) {
    const void* n    = d_in[0];
    const void* e    = d_in[1];
    const void* W    = d_in[2];
    const void* bptr = d_in[3];
    const int* hn4 = (const int*)d_in[4];
    const int* he4 = (const int*)d_in[5];
    const int* hn8 = (const int*)d_in[6];
    const int* he8 = (const int*)d_in[7];

    int*   flag = (int*)d_ws;
    float* part = ((float*)d_ws) + 16;   // 4500 floats, every slot written each launch

    k_detect<<<1, 64, 0, stream>>>(W, flag);
    k_rows<<<NBLK, 256, 0, stream>>>(n, e, W, bptr, hn4, he4, hn8, he8, flag, part);
    k_final<<<1, 256, 0, stream>>>(part, flag, d_out);
}